// Round 4
// baseline (158.642 us; speedup 1.0000x reference)
//
#include <hip/hip_runtime.h>
#include <math.h>

#define BB 2
#define CC 192
#define NN 16384
#define KK 16
#define COUT 192
#define MM (BB * NN)          // 32768 points
#define KDIM (2 * CC)         // 384 = GEMM K
#define EPSF 1e-5f

typedef __attribute__((ext_vector_type(8))) short short8;
typedef __attribute__((ext_vector_type(4))) float f32x4;

static __device__ __forceinline__ float bf16_to_f32(unsigned int u16) {
    return __uint_as_float(u16 << 16);
}
static __device__ __forceinline__ unsigned short f32_to_bf16(float f) {
    unsigned int u = __float_as_uint(f);
    unsigned int r = (u + 0x7fffu + ((u >> 16) & 1u)) >> 16;  // RNE
    return (unsigned short)r;
}

// ---------------------------------------------------------------------------
// Kernel 1: cast W f32 -> bf16, and zero the BN accumulators.
// NOTE: sums zeroing uses the GLOBAL index (2*COUT=384 > one block's 256
// threads). Round-3 zeroed only [0,256) -> sumsq tail accumulated across
// graph replays -> non-deterministic output. Fixed here.
// ---------------------------------------------------------------------------
__global__ void k_wcast(const float* __restrict__ W, unsigned short* __restrict__ Wb,
                        float* __restrict__ sums) {
    int i = blockIdx.x * 256 + threadIdx.x;
    if (i < 2 * COUT) sums[i] = 0.0f;
    if (i < COUT * KDIM) Wb[i] = f32_to_bf16(W[i]);
}

// ---------------------------------------------------------------------------
// Kernel 2: transpose+cast x [B,C,N] f32 -> xt [B,N,C] bf16, dword stores
// ---------------------------------------------------------------------------
__global__ __launch_bounds__(256) void k_transpose_x(const float* __restrict__ x,
                                                     unsigned int* __restrict__ xt32) {
    __shared__ float tile[64][33];
    int b = blockIdx.z;
    int n0 = blockIdx.x * 32;
    int c0 = blockIdx.y * 64;
    int tx = threadIdx.x, ty = threadIdx.y;  // (32,8)
    #pragma unroll
    for (int j = 0; j < 64; j += 8)
        tile[ty + j][tx] = x[((size_t)b * CC + (c0 + ty + j)) * NN + n0 + tx];
    __syncthreads();
    #pragma unroll
    for (int j = 0; j < 32; j += 8) {
        int n = n0 + ty + j;
        unsigned int w = (unsigned int)f32_to_bf16(tile[2 * tx][ty + j]) |
                         ((unsigned int)f32_to_bf16(tile[2 * tx + 1][ty + j]) << 16);
        xt32[(((size_t)b * NN + n) * CC + c0) / 2 + tx] = w;
    }
}

// ---------------------------------------------------------------------------
// Kernel 3 (fused): gather + max-relative -> LDS A-tile (interleaved xs/mr),
// MFMA GEMM vs Wb, epilogue writes h (bf16) + BN sum/sumsq atomics.
// Grid = 256 blocks (1/CU), 512 threads (8 waves), BM=128 points, full O=192.
// ---------------------------------------------------------------------------
#define BMF 128
__global__ __launch_bounds__(512, 1) void k_fused(const unsigned short* __restrict__ xt,
                                                  const int* __restrict__ edge,
                                                  const unsigned short* __restrict__ Wb,
                                                  unsigned short* __restrict__ h,
                                                  float* __restrict__ sums) {
    __shared__ __align__(16) char ldsA[BMF * 768];    // 96 KB
    __shared__ __align__(16) char ldsB[COUT * 128];   // 24 KB
    __shared__ int sj[BMF][KK];
    __shared__ int si[BMF][KK];
    int t = threadIdx.x;
    int m0 = blockIdx.x * BMF;
    int b = m0 >> 14;           // BMF divides NN -> whole block in one batch
    int n0 = m0 & (NN - 1);

    // stage edge indices (coalesced: contiguous [n0..n0+128) x K)
    {
        const int* ej = edge + ((size_t)b * NN + n0) * KK;
        const int* ei = edge + ((size_t)(BB + b) * NN + n0) * KK;
        for (int u = t; u < BMF * KK; u += 512) {
            ((int*)sj)[u] = ej[u];
            ((int*)si)[u] = ei[u];
        }
    }
    __syncthreads();

    // gather phase: 4 threads per point, 48 channels each
    {
        int p = t >> 2, q = t & 3;
        const unsigned short* base = xt + (size_t)b * NN * CC;
        const unsigned short* xrow = base + (size_t)(n0 + p) * CC + q * 48;
        uint4 xs[6];
        #pragma unroll
        for (int s = 0; s < 6; ++s) xs[s] = *(const uint4*)(xrow + s * 8);
        float mx[48];
        #pragma unroll
        for (int c = 0; c < 48; ++c) mx[c] = -INFINITY;
        for (int k = 0; k < KK; ++k) {
            const unsigned short* rj = base + (size_t)sj[p][k] * CC + q * 48;
            const unsigned short* ri = base + (size_t)si[p][k] * CC + q * 48;
            uint4 vj[6], vi[6];
            #pragma unroll
            for (int s = 0; s < 6; ++s) {
                vj[s] = *(const uint4*)(rj + s * 8);
                vi[s] = *(const uint4*)(ri + s * 8);
            }
            #pragma unroll
            for (int s = 0; s < 6; ++s) {
                const unsigned int dj[4] = {vj[s].x, vj[s].y, vj[s].z, vj[s].w};
                const unsigned int di[4] = {vi[s].x, vi[s].y, vi[s].z, vi[s].w};
                #pragma unroll
                for (int e = 0; e < 4; ++e) {
                    int c = s * 8 + 2 * e;
                    mx[c] = fmaxf(mx[c], bf16_to_f32(dj[e] & 0xffffu) - bf16_to_f32(di[e] & 0xffffu));
                    mx[c + 1] = fmaxf(mx[c + 1], bf16_to_f32(dj[e] >> 16) - bf16_to_f32(di[e] >> 16));
                }
            }
        }
        // write interleaved (xs,mr) to LDS A, swizzled b128 stores
        #pragma unroll
        for (int s = 0; s < 6; ++s) {
            const unsigned int dx[4] = {xs[s].x, xs[s].y, xs[s].z, xs[s].w};
            #pragma unroll
            for (int h2 = 0; h2 < 2; ++h2) {
                int a = s * 8 + 4 * h2;  // local channel base (4 channels)
                uint4 o;
                o.x = (dx[2 * h2] & 0xffffu) | ((unsigned int)f32_to_bf16(mx[a]) << 16);
                o.y = (dx[2 * h2] >> 16) | ((unsigned int)f32_to_bf16(mx[a + 1]) << 16);
                o.z = (dx[2 * h2 + 1] & 0xffffu) | ((unsigned int)f32_to_bf16(mx[a + 2]) << 16);
                o.w = (dx[2 * h2 + 1] >> 16) | ((unsigned int)f32_to_bf16(mx[a + 3]) << 16);
                int off = 192 * q + 32 * s + 16 * h2;  // byte offset in row
                *(uint4*)(ldsA + p * 768 + (off ^ ((p & 7) << 4))) = o;
            }
        }
    }
    __syncthreads();

    // MFMA phase
    int w = t >> 6, l = t & 63, lo = l & 15, q4 = l >> 4;
    f32x4 acc[12];
    #pragma unroll
    for (int i = 0; i < 12; ++i) acc[i] = (f32x4){0.f, 0.f, 0.f, 0.f};
    int rA = w * 16 + lo;

    for (int ks = 0; ks < KDIM / 64; ++ks) {
        if (ks) __syncthreads();
        // stage B: 192 rows x 128 B of this K-slice
        #pragma unroll
        for (int it = 0; it < 3; ++it) {
            int idx = t + it * 512;
            int r = idx >> 3, c = idx & 7;
            uint4 v = *(const uint4*)(Wb + (size_t)r * KDIM + ks * 64 + c * 8);
            *(uint4*)(ldsB + r * 128 + ((c * 16) ^ ((r & 7) << 4))) = v;
        }
        __syncthreads();
        #pragma unroll
        for (int kh = 0; kh < 2; ++kh) {
            int kt = ks * 2 + kh;
            int cbA = kt * 64 + q4 * 16;
            short8 a = *(const short8*)(ldsA + rA * 768 + (cbA ^ ((rA & 7) << 4)));
            int cbB = kh * 64 + q4 * 16;
            #pragma unroll
            for (int ot = 0; ot < 12; ++ot) {
                int rB = ot * 16 + lo;
                short8 bf = *(const short8*)(ldsB + rB * 128 + (cbB ^ ((rB & 7) << 4)));
                acc[ot] = __builtin_amdgcn_mfma_f32_16x16x32_bf16(a, bf, acc[ot], 0, 0, 0);
            }
        }
    }

    // epilogue: h (bf16) + BN stats. C/D layout: o = lane&15, m = q4*4+reg
    int mrow = m0 + w * 16 + q4 * 4;
    #pragma unroll
    for (int ot = 0; ot < 12; ++ot) {
        int o = ot * 16 + lo;
        float s = 0.f, s2 = 0.f;
        #pragma unroll
        for (int r = 0; r < 4; ++r) {
            float v = acc[ot][r];
            h[(size_t)(mrow + r) * COUT + o] = f32_to_bf16(v);
            s += v;
            s2 += v * v;
        }
        s += __shfl_xor(s, 16);  s2 += __shfl_xor(s2, 16);
        s += __shfl_xor(s, 32);  s2 += __shfl_xor(s2, 32);
        if (q4 == 0) {
            atomicAdd(&sums[o], s);
            atomicAdd(&sums[COUT + o], s2);
        }
    }
}

// ---------------------------------------------------------------------------
// Kernel 4: BN finalize (per-block) + GELU + transpose h [m][o] -> out [B,O,N]
// ---------------------------------------------------------------------------
__global__ __launch_bounds__(256) void k_out(const unsigned short* __restrict__ h,
                                             const float* __restrict__ sums,
                                             const float* __restrict__ gamma,
                                             const float* __restrict__ beta,
                                             float* __restrict__ out) {
    __shared__ float tile[32][33];
    __shared__ float ssc[32], ssh[32];
    int b = blockIdx.z;
    int n0 = blockIdx.x * 32;
    int o0 = blockIdx.y * 32;
    int tx = threadIdx.x, ty = threadIdx.y;  // (32,8)
    if (ty == 0) {
        int o = o0 + tx;
        float inv_m = 1.0f / (float)MM;
        float mean = sums[o] * inv_m;
        float var = sums[COUT + o] * inv_m - mean * mean;
        float sc = gamma[o] * rsqrtf(var + EPSF);
        ssc[tx] = sc;
        ssh[tx] = beta[o] - mean * sc;
    }
    __syncthreads();
    #pragma unroll
    for (int j = 0; j < 32; j += 8) {
        int o = o0 + tx;
        float v = bf16_to_f32(h[((size_t)b * NN + n0 + ty + j) * COUT + o]);
        v = v * ssc[tx] + ssh[tx];
        tile[ty + j][tx] = 0.5f * v * (1.0f + erff(v * 0.70710678118654752440f));
    }
    __syncthreads();
    #pragma unroll
    for (int j = 0; j < 32; j += 8)
        out[((size_t)b * COUT + (o0 + ty + j)) * NN + n0 + tx] = tile[tx][ty + j];
}

// ---------------------------------------------------------------------------
extern "C" void kernel_launch(void* const* d_in, const int* in_sizes, int n_in,
                              void* d_out, int out_size, void* d_ws, size_t ws_size,
                              hipStream_t stream) {
    const float* x = (const float*)d_in[0];
    const float* W = (const float*)d_in[1];
    // d_in[2] = b_conv: cancels in training-mode BN
    const float* gamma = (const float*)d_in[3];
    const float* beta = (const float*)d_in[4];
    const int* edge = (const int*)d_in[5];
    float* out = (float*)d_out;

    char* ws = (char*)d_ws;
    unsigned short* xt = (unsigned short*)ws;                 // [M][C] bf16
    ws += (size_t)MM * CC * 2;
    unsigned short* Wb = (unsigned short*)ws;                 // [COUT][2C] bf16
    ws += (size_t)COUT * KDIM * 2;
    unsigned short* h = (unsigned short*)ws;                  // [M][COUT] bf16
    ws += (size_t)MM * COUT * 2;
    float* sums = (float*)ws;                                 // [2*COUT]

    k_wcast<<<(COUT * KDIM + 255) / 256, 256, 0, stream>>>(W, Wb, sums);

    dim3 tgrid(NN / 32, CC / 64, BB);
    k_transpose_x<<<tgrid, dim3(32, 8), 0, stream>>>(x, (unsigned int*)xt);

    k_fused<<<MM / BMF, 512, 0, stream>>>(xt, edge, Wb, h, sums);

    dim3 ogrid(NN / 32, COUT / 32, BB);
    k_out<<<ogrid, dim3(32, 8), 0, stream>>>(h, sums, gamma, beta, out);
}

// Round 5
// 148.924 us; speedup vs baseline: 1.0653x; 1.0653x over previous
//
#include <hip/hip_runtime.h>
#include <math.h>

#define BB 2
#define CC 192
#define NN 16384
#define KK 16
#define COUT 192
#define MM (BB * NN)          // 32768 points
#define KDIM (2 * CC)         // 384 = GEMM K
#define EPSF 1e-5f

typedef __attribute__((ext_vector_type(8))) short short8;
typedef __attribute__((ext_vector_type(4))) float f32x4;

static __device__ __forceinline__ float bf16_to_f32(unsigned int u16) {
    return __uint_as_float(u16 << 16);
}
static __device__ __forceinline__ float bf16hi_to_f32(unsigned int u) {
    return __uint_as_float(u & 0xffff0000u);
}
static __device__ __forceinline__ unsigned short f32_to_bf16(float f) {
    unsigned int u = __float_as_uint(f);
    unsigned int r = (u + 0x7fffu + ((u >> 16) & 1u)) >> 16;  // RNE
    return (unsigned short)r;
}

// ---------------------------------------------------------------------------
// Kernel 1 (k_prep): blockIdx < 3072 -> transpose+cast x [B,C,N] -> xt [B,N,C]
// bf16; blockIdx >= 3072 -> cast W -> bf16 (72 blocks x 1024 elems) and zero
// the BN accumulators (full 2*COUT=384, split across first two W blocks).
// ---------------------------------------------------------------------------
#define TRB (512 * 3 * BB)   // 3072 transpose blocks
__global__ __launch_bounds__(256) void k_prep(const float* __restrict__ x,
                                              unsigned int* __restrict__ xt32,
                                              const float* __restrict__ W,
                                              unsigned short* __restrict__ Wb,
                                              float* __restrict__ sums) {
    int bid = blockIdx.x;
    int t = threadIdx.x;
    if (bid >= TRB) {
        int wb = bid - TRB;                       // 0..71
        if (wb < 2 && t < 192) sums[wb * 192 + t] = 0.0f;
        int base = wb * 1024 + t * 4;
        float4 v = *(const float4*)(W + base);
        uint2 o;
        o.x = (unsigned int)f32_to_bf16(v.x) | ((unsigned int)f32_to_bf16(v.y) << 16);
        o.y = (unsigned int)f32_to_bf16(v.z) | ((unsigned int)f32_to_bf16(v.w) << 16);
        *(uint2*)(Wb + base) = o;
        return;
    }
    __shared__ float tile[64][33];
    int nb = bid & 511;
    int rest = bid >> 9;
    int cb = rest % 3;
    int b = rest / 3;
    int n0 = nb * 32, c0 = cb * 64;
    int tx = t & 31, ty = t >> 5;  // (32,8)
    #pragma unroll
    for (int j = 0; j < 64; j += 8)
        tile[ty + j][tx] = x[((size_t)b * CC + (c0 + ty + j)) * NN + n0 + tx];
    __syncthreads();
    #pragma unroll
    for (int j = 0; j < 32; j += 8) {
        int n = n0 + ty + j;
        unsigned int w = (unsigned int)f32_to_bf16(tile[2 * tx][ty + j]) |
                         ((unsigned int)f32_to_bf16(tile[2 * tx + 1][ty + j]) << 16);
        xt32[(((size_t)b * NN + n) * CC + c0) / 2 + tx] = w;
    }
}

// ---------------------------------------------------------------------------
// Kernel 2 (k_gather): 8 points/block, 384 threads (48 lanes/point, uint2 per
// lane). High occupancy for latency hiding of random row gathers.
// Output xcat[m][2c] = {xs_c, mr_c} interleaved bf16 (= GEMM A layout).
// ---------------------------------------------------------------------------
__global__ __launch_bounds__(384) void k_gather(const unsigned short* __restrict__ xt,
                                                const int* __restrict__ edge,
                                                uint4* __restrict__ xcat4) {
    __shared__ int sj[8][KK], si[8][KK];
    int t = threadIdx.x;
    int m0 = blockIdx.x * 8;
    int b = m0 >> 14, n0 = m0 & (NN - 1);
    if (t < 128)
        ((int*)sj)[t] = edge[((size_t)b * NN + n0) * KK + t];
    else if (t < 256)
        ((int*)si)[t - 128] = edge[((size_t)(BB + b) * NN + n0) * KK + (t - 128)];
    __syncthreads();

    int p = t / 48, c2 = t % 48;
    const uint2* base = (const uint2*)(xt + (size_t)b * NN * CC) + c2;
    float mx0 = -INFINITY, mx1 = -INFINITY, mx2 = -INFINITY, mx3 = -INFINITY;
    #pragma unroll
    for (int k = 0; k < KK; ++k) {
        uint2 uj = base[(size_t)sj[p][k] * 48];
        uint2 ui = base[(size_t)si[p][k] * 48];
        mx0 = fmaxf(mx0, bf16_to_f32(uj.x << 16 >> 16 == 0 ? uj.x & 0xffffu : uj.x & 0xffffu) - bf16_to_f32(ui.x & 0xffffu));
        mx1 = fmaxf(mx1, bf16hi_to_f32(uj.x) - bf16hi_to_f32(ui.x));
        mx2 = fmaxf(mx2, bf16_to_f32(uj.y & 0xffffu) - bf16_to_f32(ui.y & 0xffffu));
        mx3 = fmaxf(mx3, bf16hi_to_f32(uj.y) - bf16hi_to_f32(ui.y));
    }
    uint2 xs = base[(size_t)(n0 + p) * 48];
    uint4 o;
    o.x = (xs.x & 0xffffu) | ((unsigned int)f32_to_bf16(mx0) << 16);
    o.y = (xs.x >> 16) | ((unsigned int)f32_to_bf16(mx1) << 16);
    o.z = (xs.y & 0xffffu) | ((unsigned int)f32_to_bf16(mx2) << 16);
    o.w = (xs.y >> 16) | ((unsigned int)f32_to_bf16(mx3) << 16);
    xcat4[(size_t)(m0 + p) * 48 + c2] = o;
}

// ---------------------------------------------------------------------------
// Kernel 3 (k_gemm): MFMA GEMM h[m][o] = sum_k xcat[m][k]*Wb[o][k], bf16 in,
// f32 acc, bf16 out; fused BN sum/sumsq atomics in the epilogue.
// Grid 256 (1 block/CU), 512 threads, BM=128 x O=192, BK=64.
// ---------------------------------------------------------------------------
#define BMT 128
__global__ __launch_bounds__(512) void k_gemm(const unsigned short* __restrict__ xcat,
                                              const unsigned short* __restrict__ Wb,
                                              unsigned short* __restrict__ h,
                                              float* __restrict__ sums) {
    __shared__ __align__(16) char ldsA[BMT * 128];    // 16 KB
    __shared__ __align__(16) char ldsB[COUT * 128];   // 24 KB
    int t = threadIdx.x;
    int m0 = blockIdx.x * BMT;
    int w = t >> 6, l = t & 63, lo = l & 15, q4 = l >> 4;
    f32x4 acc[12];
    #pragma unroll
    for (int i = 0; i < 12; ++i) acc[i] = (f32x4){0.f, 0.f, 0.f, 0.f};
    int rA = w * 16 + lo;

    for (int ks = 0; ks < KDIM / 64; ++ks) {
        int k0 = ks * 64;
        if (ks) __syncthreads();
        // stage A: 128 rows x 128 B of this K-slice
        #pragma unroll
        for (int it = 0; it < 2; ++it) {
            int idx = t + it * 512;
            int r = idx >> 3, c = idx & 7;
            uint4 v = *(const uint4*)(xcat + (size_t)(m0 + r) * KDIM + k0 + c * 8);
            *(uint4*)(ldsA + r * 128 + ((c * 16) ^ ((r & 7) << 4))) = v;
        }
        // stage B: 192 rows x 128 B
        #pragma unroll
        for (int it = 0; it < 3; ++it) {
            int idx = t + it * 512;
            int r = idx >> 3, c = idx & 7;
            uint4 v = *(const uint4*)(Wb + (size_t)r * KDIM + k0 + c * 8);
            *(uint4*)(ldsB + r * 128 + ((c * 16) ^ ((r & 7) << 4))) = v;
        }
        __syncthreads();
        #pragma unroll
        for (int kh = 0; kh < 2; ++kh) {
            int cb = kh * 64 + q4 * 16;
            short8 a = *(const short8*)(ldsA + rA * 128 + (cb ^ ((rA & 7) << 4)));
            #pragma unroll
            for (int ot = 0; ot < 12; ++ot) {
                int rB = ot * 16 + lo;
                short8 bf = *(const short8*)(ldsB + rB * 128 + (cb ^ ((rB & 7) << 4)));
                acc[ot] = __builtin_amdgcn_mfma_f32_16x16x32_bf16(a, bf, acc[ot], 0, 0, 0);
            }
        }
    }
    // epilogue: h (bf16) + BN stats. C/D layout: o = lane&15, m = q4*4+reg
    int mrow = m0 + w * 16 + q4 * 4;
    #pragma unroll
    for (int ot = 0; ot < 12; ++ot) {
        int o = ot * 16 + lo;
        float s = 0.f, s2 = 0.f;
        #pragma unroll
        for (int r = 0; r < 4; ++r) {
            float v = acc[ot][r];
            h[(size_t)(mrow + r) * COUT + o] = f32_to_bf16(v);
            s += v;
            s2 += v * v;
        }
        s += __shfl_xor(s, 16);  s2 += __shfl_xor(s2, 16);
        s += __shfl_xor(s, 32);  s2 += __shfl_xor(s2, 32);
        if (q4 == 0) {
            atomicAdd(&sums[o], s);
            atomicAdd(&sums[COUT + o], s2);
        }
    }
}

// ---------------------------------------------------------------------------
// Kernel 4 (k_out): BN finalize (per-block) + exact GELU + transpose
// h [m][o] -> out [B,O,N] f32
// ---------------------------------------------------------------------------
__global__ __launch_bounds__(256) void k_out(const unsigned short* __restrict__ h,
                                             const float* __restrict__ sums,
                                             const float* __restrict__ gamma,
                                             const float* __restrict__ beta,
                                             float* __restrict__ out) {
    __shared__ float tile[32][33];
    __shared__ float ssc[32], ssh[32];
    int b = blockIdx.z;
    int n0 = blockIdx.x * 32;
    int o0 = blockIdx.y * 32;
    int tx = threadIdx.x, ty = threadIdx.y;  // (32,8)
    if (ty == 0) {
        int o = o0 + tx;
        float inv_m = 1.0f / (float)MM;
        float mean = sums[o] * inv_m;
        float var = sums[COUT + o] * inv_m - mean * mean;
        float sc = gamma[o] * rsqrtf(var + EPSF);
        ssc[tx] = sc;
        ssh[tx] = beta[o] - mean * sc;
    }
    __syncthreads();
    #pragma unroll
    for (int j = 0; j < 32; j += 8) {
        int o = o0 + tx;
        float v = bf16_to_f32(h[((size_t)b * NN + n0 + ty + j) * COUT + o]);
        v = v * ssc[tx] + ssh[tx];
        tile[ty + j][tx] = 0.5f * v * (1.0f + erff(v * 0.70710678118654752440f));
    }
    __syncthreads();
    #pragma unroll
    for (int j = 0; j < 32; j += 8)
        out[((size_t)b * COUT + (o0 + ty + j)) * NN + n0 + tx] = tile[tx][ty + j];
}

// ---------------------------------------------------------------------------
extern "C" void kernel_launch(void* const* d_in, const int* in_sizes, int n_in,
                              void* d_out, int out_size, void* d_ws, size_t ws_size,
                              hipStream_t stream) {
    const float* x = (const float*)d_in[0];
    const float* W = (const float*)d_in[1];
    // d_in[2] = b_conv: cancels in training-mode BN
    const float* gamma = (const float*)d_in[3];
    const float* beta = (const float*)d_in[4];
    const int* edge = (const int*)d_in[5];
    float* out = (float*)d_out;

    char* ws = (char*)d_ws;
    unsigned short* xt = (unsigned short*)ws;                 // [M][C] bf16
    ws += (size_t)MM * CC * 2;
    unsigned short* xcat = (unsigned short*)ws;               // [M][2C] bf16
    ws += (size_t)MM * KDIM * 2;
    unsigned short* Wb = (unsigned short*)ws;                 // [COUT][2C] bf16
    ws += (size_t)COUT * KDIM * 2;
    unsigned short* h = (unsigned short*)ws;                  // [M][COUT] bf16
    ws += (size_t)MM * COUT * 2;
    float* sums = (float*)ws;                                 // [2*COUT]

    k_prep<<<TRB + 72, 256, 0, stream>>>(x, (unsigned int*)xt, W, Wb, sums);

    k_gather<<<MM / 8, 384, 0, stream>>>(xt, edge, (uint4*)xcat);

    k_gemm<<<MM / BMT, 512, 0, stream>>>(xcat, Wb, h, sums);

    dim3 ogrid(NN / 32, COUT / 32, BB);
    k_out<<<ogrid, dim3(32, 8), 0, stream>>>(h, sums, gamma, beta, out);
}

// Round 6
// 94.031 us; speedup vs baseline: 1.6871x; 1.5838x over previous
//
#include <hip/hip_runtime.h>
#include <math.h>

#define BB 2
#define CC 192
#define NN 16384
#define KK 16
#define COUT 192
#define MM (BB * NN)          // 32768 points
#define KDIM (2 * CC)         // 384 = GEMM K
#define EPSF 1e-5f
#define NGB 256               // gemm grid (partial-sum rows)

typedef __attribute__((ext_vector_type(8))) short short8;
typedef __attribute__((ext_vector_type(4))) float f32x4;

static __device__ __forceinline__ float bf16_to_f32(unsigned int u16) {
    return __uint_as_float(u16 << 16);
}
static __device__ __forceinline__ float bf16hi_to_f32(unsigned int u) {
    return __uint_as_float(u & 0xffff0000u);
}
static __device__ __forceinline__ unsigned short f32_to_bf16(float f) {
    unsigned int u = __float_as_uint(f);
    unsigned int r = (u + 0x7fffu + ((u >> 16) & 1u)) >> 16;  // RNE
    return (unsigned short)r;
}

// ---------------------------------------------------------------------------
// Kernel 1 (k_prep): blockIdx < 3072 -> transpose+cast x [B,C,N] -> xt [B,N,C]
// bf16; blockIdx >= 3072 -> cast W -> bf16 (72 blocks x 1024 elems).
// ---------------------------------------------------------------------------
#define TRB (512 * 3 * BB)   // 3072 transpose blocks
__global__ __launch_bounds__(256) void k_prep(const float* __restrict__ x,
                                              unsigned int* __restrict__ xt32,
                                              const float* __restrict__ W,
                                              unsigned short* __restrict__ Wb) {
    int bid = blockIdx.x;
    int t = threadIdx.x;
    if (bid >= TRB) {
        int wb = bid - TRB;                       // 0..71
        int base = wb * 1024 + t * 4;
        float4 v = *(const float4*)(W + base);
        uint2 o;
        o.x = (unsigned int)f32_to_bf16(v.x) | ((unsigned int)f32_to_bf16(v.y) << 16);
        o.y = (unsigned int)f32_to_bf16(v.z) | ((unsigned int)f32_to_bf16(v.w) << 16);
        *(uint2*)(Wb + base) = o;
        return;
    }
    __shared__ float tile[64][33];
    int nb = bid & 511;
    int rest = bid >> 9;
    int cb = rest % 3;
    int b = rest / 3;
    int n0 = nb * 32, c0 = cb * 64;
    int tx = t & 31, ty = t >> 5;  // (32,8)
    #pragma unroll
    for (int j = 0; j < 64; j += 8)
        tile[ty + j][tx] = x[((size_t)b * CC + (c0 + ty + j)) * NN + n0 + tx];
    __syncthreads();
    #pragma unroll
    for (int j = 0; j < 32; j += 8) {
        int n = n0 + ty + j;
        unsigned int w = (unsigned int)f32_to_bf16(tile[2 * tx][ty + j]) |
                         ((unsigned int)f32_to_bf16(tile[2 * tx + 1][ty + j]) << 16);
        xt32[(((size_t)b * NN + n) * CC + c0) / 2 + tx] = w;
    }
}

// ---------------------------------------------------------------------------
// Kernel 2 (k_gather): 8 points/block, 384 threads (48 lanes/point, uint2 per
// lane). High occupancy for latency hiding of random row gathers.
// Output xcat[m][2c] = {xs_c, mr_c} interleaved bf16 (= GEMM A layout).
// ---------------------------------------------------------------------------
__global__ __launch_bounds__(384) void k_gather(const unsigned short* __restrict__ xt,
                                                const int* __restrict__ edge,
                                                uint4* __restrict__ xcat4) {
    __shared__ int sj[8][KK], si[8][KK];
    int t = threadIdx.x;
    int m0 = blockIdx.x * 8;
    int b = m0 >> 14, n0 = m0 & (NN - 1);
    if (t < 128)
        ((int*)sj)[t] = edge[((size_t)b * NN + n0) * KK + t];
    else if (t < 256)
        ((int*)si)[t - 128] = edge[((size_t)(BB + b) * NN + n0) * KK + (t - 128)];
    __syncthreads();

    int p = t / 48, c2 = t % 48;
    const uint2* base = (const uint2*)(xt + (size_t)b * NN * CC) + c2;
    float mx0 = -INFINITY, mx1 = -INFINITY, mx2 = -INFINITY, mx3 = -INFINITY;
    #pragma unroll
    for (int k = 0; k < KK; ++k) {
        uint2 uj = base[(size_t)sj[p][k] * 48];
        uint2 ui = base[(size_t)si[p][k] * 48];
        mx0 = fmaxf(mx0, bf16_to_f32(uj.x & 0xffffu) - bf16_to_f32(ui.x & 0xffffu));
        mx1 = fmaxf(mx1, bf16hi_to_f32(uj.x) - bf16hi_to_f32(ui.x));
        mx2 = fmaxf(mx2, bf16_to_f32(uj.y & 0xffffu) - bf16_to_f32(ui.y & 0xffffu));
        mx3 = fmaxf(mx3, bf16hi_to_f32(uj.y) - bf16hi_to_f32(ui.y));
    }
    uint2 xs = base[(size_t)(n0 + p) * 48];
    uint4 o;
    o.x = (xs.x & 0xffffu) | ((unsigned int)f32_to_bf16(mx0) << 16);
    o.y = (xs.x >> 16) | ((unsigned int)f32_to_bf16(mx1) << 16);
    o.z = (xs.y & 0xffffu) | ((unsigned int)f32_to_bf16(mx2) << 16);
    o.w = (xs.y >> 16) | ((unsigned int)f32_to_bf16(mx3) << 16);
    xcat4[(size_t)(m0 + p) * 48 + c2] = o;
}

// ---------------------------------------------------------------------------
// Kernel 3 (k_gemm): MFMA GEMM h[m][o] = sum_k xcat[m][k]*Wb[o][k], bf16 in,
// f32 acc, bf16 out. BN stats: cross-wave LDS reduce -> ONE partial-sum row
// per block (psum/psum2[block][o]) -- NO global atomics (round-5's 108 us was
// 2048-deep same-address atomic chains).
// Grid 256 (1 block/CU), 512 threads, BM=128 x O=192, BK=64.
// ---------------------------------------------------------------------------
#define BMT 128
__global__ __launch_bounds__(512) void k_gemm(const unsigned short* __restrict__ xcat,
                                              const unsigned short* __restrict__ Wb,
                                              unsigned short* __restrict__ h,
                                              float* __restrict__ psum,
                                              float* __restrict__ psum2) {
    __shared__ __align__(16) char ldsA[BMT * 128];    // 16 KB (reused for reduce)
    __shared__ __align__(16) char ldsB[COUT * 128];   // 24 KB
    int t = threadIdx.x;
    int m0 = blockIdx.x * BMT;
    int w = t >> 6, l = t & 63, lo = l & 15, q4 = l >> 4;
    f32x4 acc[12];
    #pragma unroll
    for (int i = 0; i < 12; ++i) acc[i] = (f32x4){0.f, 0.f, 0.f, 0.f};
    int rA = w * 16 + lo;

    for (int ks = 0; ks < KDIM / 64; ++ks) {
        int k0 = ks * 64;
        if (ks) __syncthreads();
        // stage A: 128 rows x 128 B of this K-slice
        #pragma unroll
        for (int it = 0; it < 2; ++it) {
            int idx = t + it * 512;
            int r = idx >> 3, c = idx & 7;
            uint4 v = *(const uint4*)(xcat + (size_t)(m0 + r) * KDIM + k0 + c * 8);
            *(uint4*)(ldsA + r * 128 + ((c * 16) ^ ((r & 7) << 4))) = v;
        }
        // stage B: 192 rows x 128 B
        #pragma unroll
        for (int it = 0; it < 3; ++it) {
            int idx = t + it * 512;
            int r = idx >> 3, c = idx & 7;
            uint4 v = *(const uint4*)(Wb + (size_t)r * KDIM + k0 + c * 8);
            *(uint4*)(ldsB + r * 128 + ((c * 16) ^ ((r & 7) << 4))) = v;
        }
        __syncthreads();
        #pragma unroll
        for (int kh = 0; kh < 2; ++kh) {
            int cb = kh * 64 + q4 * 16;
            short8 a = *(const short8*)(ldsA + rA * 128 + (cb ^ ((rA & 7) << 4)));
            #pragma unroll
            for (int ot = 0; ot < 12; ++ot) {
                int rB = ot * 16 + lo;
                short8 bf = *(const short8*)(ldsB + rB * 128 + (cb ^ ((rB & 7) << 4)));
                acc[ot] = __builtin_amdgcn_mfma_f32_16x16x32_bf16(a, bf, acc[ot], 0, 0, 0);
            }
        }
    }
    __syncthreads();  // all waves done with ldsA before the reduce overlay

    // epilogue: h (bf16) + per-wave BN sums into LDS. C/D: o=lane&15, m=q4*4+r
    float* reds = (float*)ldsA;              // [8][COUT]
    float* reds2 = reds + 8 * COUT;          // [8][COUT]  (12 KB total <= 16 KB)
    int mrow = m0 + w * 16 + q4 * 4;
    #pragma unroll
    for (int ot = 0; ot < 12; ++ot) {
        int o = ot * 16 + lo;
        float s = 0.f, s2 = 0.f;
        #pragma unroll
        for (int r = 0; r < 4; ++r) {
            float v = acc[ot][r];
            h[(size_t)(mrow + r) * COUT + o] = f32_to_bf16(v);
            s += v;
            s2 += v * v;
        }
        s += __shfl_xor(s, 16);  s2 += __shfl_xor(s2, 16);
        s += __shfl_xor(s, 32);  s2 += __shfl_xor(s2, 32);
        if (q4 == 0) {
            reds[w * COUT + o] = s;
            reds2[w * COUT + o] = s2;
        }
    }
    __syncthreads();
    if (t < COUT) {
        float a = 0.f, a2 = 0.f;
        #pragma unroll
        for (int w8 = 0; w8 < 8; ++w8) {
            a += reds[w8 * COUT + t];
            a2 += reds2[w8 * COUT + t];
        }
        psum[blockIdx.x * COUT + t] = a;
        psum2[blockIdx.x * COUT + t] = a2;
    }
}

// ---------------------------------------------------------------------------
// Kernel 4 (k_out): reduce BN partials for this o-tile + finalize + exact GELU
// + transpose h [m][o] -> out [B,O,N] f32
// ---------------------------------------------------------------------------
__global__ __launch_bounds__(256) void k_out(const unsigned short* __restrict__ h,
                                             const float* __restrict__ psum,
                                             const float* __restrict__ psum2,
                                             const float* __restrict__ gamma,
                                             const float* __restrict__ beta,
                                             float* __restrict__ out) {
    __shared__ float tile[32][33];
    __shared__ float rs[8][32], rs2[8][32];
    __shared__ float ssc[32], ssh[32];
    int b = blockIdx.z;
    int n0 = blockIdx.x * 32;
    int o0 = blockIdx.y * 32;
    int tx = threadIdx.x, ty = threadIdx.y;  // (32,8)
    int o = o0 + tx;
    {
        float a = 0.f, a2 = 0.f;
        for (int i = ty; i < NGB; i += 8) {
            a += psum[i * COUT + o];
            a2 += psum2[i * COUT + o];
        }
        rs[ty][tx] = a;
        rs2[ty][tx] = a2;
    }
    __syncthreads();
    if (ty == 0) {
        float a = rs[0][tx], a2 = rs2[0][tx];
        #pragma unroll
        for (int i = 1; i < 8; ++i) { a += rs[i][tx]; a2 += rs2[i][tx]; }
        float inv_m = 1.0f / (float)MM;
        float mean = a * inv_m;
        float var = a2 * inv_m - mean * mean;
        float sc = gamma[o] * rsqrtf(var + EPSF);
        ssc[tx] = sc;
        ssh[tx] = beta[o] - mean * sc;
    }
    __syncthreads();
    #pragma unroll
    for (int j = 0; j < 32; j += 8) {
        float v = bf16_to_f32(h[((size_t)b * NN + n0 + ty + j) * COUT + o]);
        v = v * ssc[tx] + ssh[tx];
        tile[ty + j][tx] = 0.5f * v * (1.0f + erff(v * 0.70710678118654752440f));
    }
    __syncthreads();
    #pragma unroll
    for (int j = 0; j < 32; j += 8)
        out[((size_t)b * COUT + (o0 + ty + j)) * NN + n0 + tx] = tile[tx][ty + j];
}

// ---------------------------------------------------------------------------
extern "C" void kernel_launch(void* const* d_in, const int* in_sizes, int n_in,
                              void* d_out, int out_size, void* d_ws, size_t ws_size,
                              hipStream_t stream) {
    const float* x = (const float*)d_in[0];
    const float* W = (const float*)d_in[1];
    // d_in[2] = b_conv: cancels in training-mode BN
    const float* gamma = (const float*)d_in[3];
    const float* beta = (const float*)d_in[4];
    const int* edge = (const int*)d_in[5];
    float* out = (float*)d_out;

    char* ws = (char*)d_ws;
    unsigned short* xt = (unsigned short*)ws;                 // [M][C] bf16
    ws += (size_t)MM * CC * 2;
    unsigned short* xcat = (unsigned short*)ws;               // [M][2C] bf16
    ws += (size_t)MM * KDIM * 2;
    unsigned short* Wb = (unsigned short*)ws;                 // [COUT][2C] bf16
    ws += (size_t)COUT * KDIM * 2;
    unsigned short* h = (unsigned short*)ws;                  // [M][COUT] bf16
    ws += (size_t)MM * COUT * 2;
    float* psum = (float*)ws;                                 // [NGB][COUT]
    ws += (size_t)NGB * COUT * sizeof(float);
    float* psum2 = (float*)ws;                                // [NGB][COUT]

    k_prep<<<TRB + 72, 256, 0, stream>>>(x, (unsigned int*)xt, W, Wb);

    k_gather<<<MM / 8, 384, 0, stream>>>(xt, edge, (uint4*)xcat);

    k_gemm<<<MM / BMT, 512, 0, stream>>>(xcat, Wb, h, psum, psum2);

    dim3 ogrid(NN / 32, COUT / 32, BB);
    k_out<<<ogrid, dim3(32, 8), 0, stream>>>(h, psum, psum2, gamma, beta, out);
}

// Round 7
// 80.615 us; speedup vs baseline: 1.9679x; 1.1664x over previous
//
#include <hip/hip_runtime.h>
#include <math.h>

#define BB 2
#define CC 192
#define NN 16384
#define KK 16
#define COUT 192
#define MM (BB * NN)          // 32768 points
#define KDIM (2 * CC)         // 384 = GEMM K
#define EPSF 1e-5f
#define NGB 256               // gemm grid (partial-sum rows)

typedef __attribute__((ext_vector_type(8))) short short8;
typedef __attribute__((ext_vector_type(4))) float f32x4;

static __device__ __forceinline__ float bf16_to_f32(unsigned int u16) {
    return __uint_as_float(u16 << 16);
}
static __device__ __forceinline__ float bf16hi_to_f32(unsigned int u) {
    return __uint_as_float(u & 0xffff0000u);
}
static __device__ __forceinline__ unsigned short f32_to_bf16(float f) {
    unsigned int u = __float_as_uint(f);
    unsigned int r = (u + 0x7fffu + ((u >> 16) & 1u)) >> 16;  // RNE
    return (unsigned short)r;
}

// ---------------------------------------------------------------------------
// Kernel 1 (k_prep): blockIdx < 3072 -> transpose+cast x [B,C,N] -> xt [B,N,C]
// bf16; blockIdx >= 3072 -> cast W -> bf16 (72 blocks x 1024 elems).
// ---------------------------------------------------------------------------
#define TRB (512 * 3 * BB)   // 3072 transpose blocks
__global__ __launch_bounds__(256) void k_prep(const float* __restrict__ x,
                                              unsigned int* __restrict__ xt32,
                                              const float* __restrict__ W,
                                              unsigned short* __restrict__ Wb) {
    int bid = blockIdx.x;
    int t = threadIdx.x;
    if (bid >= TRB) {
        int wb = bid - TRB;                       // 0..71
        int base = wb * 1024 + t * 4;
        float4 v = *(const float4*)(W + base);
        uint2 o;
        o.x = (unsigned int)f32_to_bf16(v.x) | ((unsigned int)f32_to_bf16(v.y) << 16);
        o.y = (unsigned int)f32_to_bf16(v.z) | ((unsigned int)f32_to_bf16(v.w) << 16);
        *(uint2*)(Wb + base) = o;
        return;
    }
    __shared__ float tile[64][33];
    int nb = bid & 511;
    int rest = bid >> 9;
    int cb = rest % 3;
    int b = rest / 3;
    int n0 = nb * 32, c0 = cb * 64;
    int tx = t & 31, ty = t >> 5;  // (32,8)
    #pragma unroll
    for (int j = 0; j < 64; j += 8)
        tile[ty + j][tx] = x[((size_t)b * CC + (c0 + ty + j)) * NN + n0 + tx];
    __syncthreads();
    #pragma unroll
    for (int j = 0; j < 32; j += 8) {
        int n = n0 + ty + j;
        unsigned int w = (unsigned int)f32_to_bf16(tile[2 * tx][ty + j]) |
                         ((unsigned int)f32_to_bf16(tile[2 * tx + 1][ty + j]) << 16);
        xt32[(((size_t)b * NN + n) * CC + c0) / 2 + tx] = w;
    }
}

// ---------------------------------------------------------------------------
// Kernel 2 (k_gather): 8 points/block, 384 threads (48 lanes/point, uint2 per
// lane). High occupancy for latency hiding of random row gathers.
// Output xcat[m][2c] = {xs_c, mr_c} interleaved bf16 (= GEMM A layout).
// ---------------------------------------------------------------------------
__global__ __launch_bounds__(384) void k_gather(const unsigned short* __restrict__ xt,
                                                const int* __restrict__ edge,
                                                uint4* __restrict__ xcat4) {
    __shared__ int sj[8][KK], si[8][KK];
    int t = threadIdx.x;
    int m0 = blockIdx.x * 8;
    int b = m0 >> 14, n0 = m0 & (NN - 1);
    if (t < 128)
        ((int*)sj)[t] = edge[((size_t)b * NN + n0) * KK + t];
    else if (t < 256)
        ((int*)si)[t - 128] = edge[((size_t)(BB + b) * NN + n0) * KK + (t - 128)];
    __syncthreads();

    int p = t / 48, c2 = t % 48;
    const uint2* base = (const uint2*)(xt + (size_t)b * NN * CC) + c2;
    float mx0 = -INFINITY, mx1 = -INFINITY, mx2 = -INFINITY, mx3 = -INFINITY;
    #pragma unroll
    for (int k = 0; k < KK; ++k) {
        uint2 uj = base[(size_t)sj[p][k] * 48];
        uint2 ui = base[(size_t)si[p][k] * 48];
        mx0 = fmaxf(mx0, bf16_to_f32(uj.x & 0xffffu) - bf16_to_f32(ui.x & 0xffffu));
        mx1 = fmaxf(mx1, bf16hi_to_f32(uj.x) - bf16hi_to_f32(ui.x));
        mx2 = fmaxf(mx2, bf16_to_f32(uj.y & 0xffffu) - bf16_to_f32(ui.y & 0xffffu));
        mx3 = fmaxf(mx3, bf16hi_to_f32(uj.y) - bf16hi_to_f32(ui.y));
    }
    uint2 xs = base[(size_t)(n0 + p) * 48];
    uint4 o;
    o.x = (xs.x & 0xffffu) | ((unsigned int)f32_to_bf16(mx0) << 16);
    o.y = (xs.x >> 16) | ((unsigned int)f32_to_bf16(mx1) << 16);
    o.z = (xs.y & 0xffffu) | ((unsigned int)f32_to_bf16(mx2) << 16);
    o.w = (xs.y >> 16) | ((unsigned int)f32_to_bf16(mx3) << 16);
    xcat4[(size_t)(m0 + p) * 48 + c2] = o;
}

// ---------------------------------------------------------------------------
// Kernel 3 (k_gemm): MFMA GEMM h[m][o] = sum_k xcat[m][k]*Wb[o][k], bf16 in,
// f32 acc, bf16 out. BN stats: cross-wave LDS reduce -> ONE partial-sum row
// per block (psum/psum2[block][o]) -- no global atomics.
// Grid 256 (1 block/CU), 512 threads, BM=128 x O=192, BK=64.
// ---------------------------------------------------------------------------
#define BMT 128
__global__ __launch_bounds__(512) void k_gemm(const unsigned short* __restrict__ xcat,
                                              const unsigned short* __restrict__ Wb,
                                              unsigned short* __restrict__ h,
                                              float* __restrict__ psum,
                                              float* __restrict__ psum2) {
    __shared__ __align__(16) char ldsA[BMT * 128];    // 16 KB (reused for reduce)
    __shared__ __align__(16) char ldsB[COUT * 128];   // 24 KB
    int t = threadIdx.x;
    int m0 = blockIdx.x * BMT;
    int w = t >> 6, l = t & 63, lo = l & 15, q4 = l >> 4;
    f32x4 acc[12];
    #pragma unroll
    for (int i = 0; i < 12; ++i) acc[i] = (f32x4){0.f, 0.f, 0.f, 0.f};
    int rA = w * 16 + lo;

    for (int ks = 0; ks < KDIM / 64; ++ks) {
        int k0 = ks * 64;
        if (ks) __syncthreads();
        // stage A: 128 rows x 128 B of this K-slice
        #pragma unroll
        for (int it = 0; it < 2; ++it) {
            int idx = t + it * 512;
            int r = idx >> 3, c = idx & 7;
            uint4 v = *(const uint4*)(xcat + (size_t)(m0 + r) * KDIM + k0 + c * 8);
            *(uint4*)(ldsA + r * 128 + ((c * 16) ^ ((r & 7) << 4))) = v;
        }
        // stage B: 192 rows x 128 B
        #pragma unroll
        for (int it = 0; it < 3; ++it) {
            int idx = t + it * 512;
            int r = idx >> 3, c = idx & 7;
            uint4 v = *(const uint4*)(Wb + (size_t)r * KDIM + k0 + c * 8);
            *(uint4*)(ldsB + r * 128 + ((c * 16) ^ ((r & 7) << 4))) = v;
        }
        __syncthreads();
        #pragma unroll
        for (int kh = 0; kh < 2; ++kh) {
            int cb = kh * 64 + q4 * 16;
            short8 a = *(const short8*)(ldsA + rA * 128 + (cb ^ ((rA & 7) << 4)));
            #pragma unroll
            for (int ot = 0; ot < 12; ++ot) {
                int rB = ot * 16 + lo;
                short8 bf = *(const short8*)(ldsB + rB * 128 + (cb ^ ((rB & 7) << 4)));
                acc[ot] = __builtin_amdgcn_mfma_f32_16x16x32_bf16(a, bf, acc[ot], 0, 0, 0);
            }
        }
    }
    __syncthreads();  // all waves done with ldsA before the reduce overlay

    // epilogue: h (bf16) + per-wave BN sums into LDS. C/D: o=lane&15, m=q4*4+r
    float* reds = (float*)ldsA;              // [8][COUT]
    float* reds2 = reds + 8 * COUT;          // [8][COUT]
    int mrow = m0 + w * 16 + q4 * 4;
    #pragma unroll
    for (int ot = 0; ot < 12; ++ot) {
        int o = ot * 16 + lo;
        float s = 0.f, s2 = 0.f;
        #pragma unroll
        for (int r = 0; r < 4; ++r) {
            float v = acc[ot][r];
            h[(size_t)(mrow + r) * COUT + o] = f32_to_bf16(v);
            s += v;
            s2 += v * v;
        }
        s += __shfl_xor(s, 16);  s2 += __shfl_xor(s2, 16);
        s += __shfl_xor(s, 32);  s2 += __shfl_xor(s2, 32);
        if (q4 == 0) {
            reds[w * COUT + o] = s;
            reds2[w * COUT + o] = s2;
        }
    }
    __syncthreads();
    if (t < COUT) {
        float a = 0.f, a2 = 0.f;
        #pragma unroll
        for (int w8 = 0; w8 < 8; ++w8) {
            a += reds[w8 * COUT + t];
            a2 += reds2[w8 * COUT + t];
        }
        psum[blockIdx.x * COUT + t] = a;
        psum2[blockIdx.x * COUT + t] = a2;
    }
}

// ---------------------------------------------------------------------------
// Kernel 4 (k_bn): reduce the 256 partial rows ONCE -> sc_sh[384].
// One block, 384 threads: t<192 reduces psum, t>=192 reduces psum2.
// (Round-6 did this reduce redundantly in all 6144 k_out blocks: 41 us.)
// ---------------------------------------------------------------------------
__global__ __launch_bounds__(384) void k_bn(const float* __restrict__ psum,
                                            const float* __restrict__ psum2,
                                            const float* __restrict__ gamma,
                                            const float* __restrict__ beta,
                                            float* __restrict__ sc_sh) {
    __shared__ float sa[COUT], sa2[COUT];
    int t = threadIdx.x;
    int o = t & (COUT - 1);  // COUT=192 not pow2 -> use explicit split
    if (t < COUT) {
        float a = 0.f;
        #pragma unroll 8
        for (int i = 0; i < NGB; ++i) a += psum[i * COUT + t];
        sa[t] = a;
    } else {
        int oo = t - COUT;
        float a2 = 0.f;
        #pragma unroll 8
        for (int i = 0; i < NGB; ++i) a2 += psum2[i * COUT + oo];
        sa2[oo] = a2;
    }
    __syncthreads();
    if (t < COUT) {
        float inv_m = 1.0f / (float)MM;
        float mean = sa[t] * inv_m;
        float var = sa2[t] * inv_m - mean * mean;
        float sc = gamma[t] * rsqrtf(var + EPSF);
        sc_sh[t] = sc;
        sc_sh[COUT + t] = beta[t] - mean * sc;
    }
    (void)o;
}

// ---------------------------------------------------------------------------
// Kernel 5 (k_out): BN apply + exact GELU + transpose h [m][o] -> out [B,O,N]
// ---------------------------------------------------------------------------
__global__ __launch_bounds__(256) void k_out(const unsigned short* __restrict__ h,
                                             const float* __restrict__ sc_sh,
                                             float* __restrict__ out) {
    __shared__ float tile[32][33];
    int b = blockIdx.z;
    int n0 = blockIdx.x * 32;
    int o0 = blockIdx.y * 32;
    int tx = threadIdx.x, ty = threadIdx.y;  // (32,8)
    int o = o0 + tx;
    float sc = sc_sh[o];
    float sh = sc_sh[COUT + o];
    #pragma unroll
    for (int j = 0; j < 32; j += 8) {
        float v = bf16_to_f32(h[((size_t)b * NN + n0 + ty + j) * COUT + o]);
        v = v * sc + sh;
        tile[ty + j][tx] = 0.5f * v * (1.0f + erff(v * 0.70710678118654752440f));
    }
    __syncthreads();
    #pragma unroll
    for (int j = 0; j < 32; j += 8)
        out[((size_t)b * COUT + (o0 + ty + j)) * NN + n0 + tx] = tile[tx][ty + j];
}

// ---------------------------------------------------------------------------
extern "C" void kernel_launch(void* const* d_in, const int* in_sizes, int n_in,
                              void* d_out, int out_size, void* d_ws, size_t ws_size,
                              hipStream_t stream) {
    const float* x = (const float*)d_in[0];
    const float* W = (const float*)d_in[1];
    // d_in[2] = b_conv: cancels in training-mode BN
    const float* gamma = (const float*)d_in[3];
    const float* beta = (const float*)d_in[4];
    const int* edge = (const int*)d_in[5];
    float* out = (float*)d_out;

    char* ws = (char*)d_ws;
    unsigned short* xt = (unsigned short*)ws;                 // [M][C] bf16
    ws += (size_t)MM * CC * 2;
    unsigned short* xcat = (unsigned short*)ws;               // [M][2C] bf16
    ws += (size_t)MM * KDIM * 2;
    unsigned short* Wb = (unsigned short*)ws;                 // [COUT][2C] bf16
    ws += (size_t)COUT * KDIM * 2;
    unsigned short* h = (unsigned short*)ws;                  // [M][COUT] bf16
    ws += (size_t)MM * COUT * 2;
    float* psum = (float*)ws;                                 // [NGB][COUT]
    ws += (size_t)NGB * COUT * sizeof(float);
    float* psum2 = (float*)ws;                                // [NGB][COUT]
    ws += (size_t)NGB * COUT * sizeof(float);
    float* sc_sh = (float*)ws;                                // [2*COUT]

    k_prep<<<TRB + 72, 256, 0, stream>>>(x, (unsigned int*)xt, W, Wb);

    k_gather<<<MM / 8, 384, 0, stream>>>(xt, edge, (uint4*)xcat);

    k_gemm<<<MM / BMT, 512, 0, stream>>>(xcat, Wb, h, psum, psum2);

    k_bn<<<1, 384, 0, stream>>>(psum, psum2, gamma, beta, sc_sh);

    dim3 ogrid(NN / 32, COUT / 32, BB);
    k_out<<<ogrid, dim3(32, 8), 0, stream>>>(h, sc_sh, out);
}

// Round 8
// 73.665 us; speedup vs baseline: 2.1536x; 1.0944x over previous
//
#include <hip/hip_runtime.h>
#include <math.h>

#define BB 2
#define CC 192
#define NN 16384
#define KK 16
#define COUT 192
#define MM (BB * NN)          // 32768 points
#define KDIM (2 * CC)         // 384 = GEMM K
#define EPSF 1e-5f
#define NGB 256               // gemm grid (partial-sum rows)

typedef __attribute__((ext_vector_type(8))) short short8;
typedef __attribute__((ext_vector_type(4))) float f32x4;

#define AS1P const __attribute__((address_space(1))) void*
#define AS3P __attribute__((address_space(3))) void*

static __device__ __forceinline__ float bf16_to_f32(unsigned int u16) {
    return __uint_as_float(u16 << 16);
}
static __device__ __forceinline__ float bf16hi_to_f32(unsigned int u) {
    return __uint_as_float(u & 0xffff0000u);
}
static __device__ __forceinline__ unsigned short f32_to_bf16(float f) {
    unsigned int u = __float_as_uint(f);
    unsigned int r = (u + 0x7fffu + ((u >> 16) & 1u)) >> 16;  // RNE
    return (unsigned short)r;
}

// ---------------------------------------------------------------------------
// Kernel 1 (k_prep): blockIdx < 3072 -> transpose+cast x [B,C,N] -> xt [B,N,C]
// bf16; blockIdx >= 3072 -> cast W -> bf16 (72 blocks x 1024 elems).
// ---------------------------------------------------------------------------
#define TRB (512 * 3 * BB)   // 3072 transpose blocks
__global__ __launch_bounds__(256) void k_prep(const float* __restrict__ x,
                                              unsigned int* __restrict__ xt32,
                                              const float* __restrict__ W,
                                              unsigned short* __restrict__ Wb) {
    int bid = blockIdx.x;
    int t = threadIdx.x;
    if (bid >= TRB) {
        int wb = bid - TRB;                       // 0..71
        int base = wb * 1024 + t * 4;
        float4 v = *(const float4*)(W + base);
        uint2 o;
        o.x = (unsigned int)f32_to_bf16(v.x) | ((unsigned int)f32_to_bf16(v.y) << 16);
        o.y = (unsigned int)f32_to_bf16(v.z) | ((unsigned int)f32_to_bf16(v.w) << 16);
        *(uint2*)(Wb + base) = o;
        return;
    }
    __shared__ float tile[64][33];
    int nb = bid & 511;
    int rest = bid >> 9;
    int cb = rest % 3;
    int b = rest / 3;
    int n0 = nb * 32, c0 = cb * 64;
    int tx = t & 31, ty = t >> 5;  // (32,8)
    #pragma unroll
    for (int j = 0; j < 64; j += 8)
        tile[ty + j][tx] = x[((size_t)b * CC + (c0 + ty + j)) * NN + n0 + tx];
    __syncthreads();
    #pragma unroll
    for (int j = 0; j < 32; j += 8) {
        int n = n0 + ty + j;
        unsigned int w = (unsigned int)f32_to_bf16(tile[2 * tx][ty + j]) |
                         ((unsigned int)f32_to_bf16(tile[2 * tx + 1][ty + j]) << 16);
        xt32[(((size_t)b * NN + n) * CC + c0) / 2 + tx] = w;
    }
}

// ---------------------------------------------------------------------------
// Kernel 2 (k_gather): 16 points/block, 384 threads, 24 lanes/point with
// uint4 (16 B) loads -- half the load instructions of the uint2 version.
// Output xcat[m][2c] = {xs_c, mr_c} interleaved bf16 (= GEMM A layout).
// ---------------------------------------------------------------------------
__global__ __launch_bounds__(384) void k_gather(const unsigned short* __restrict__ xt,
                                                const int* __restrict__ edge,
                                                uint4* __restrict__ xcat4) {
    __shared__ int sj[16][KK], si[16][KK];
    int t = threadIdx.x;
    int m0 = blockIdx.x * 16;
    int b = m0 >> 14, n0 = m0 & (NN - 1);
    if (t < 256)
        ((int*)sj)[t] = edge[((size_t)b * NN + n0) * KK + t];
    if (t >= 128)
        ((int*)si)[t - 128] = edge[((size_t)(BB + b) * NN + n0) * KK + (t - 128)];
    __syncthreads();

    int p = t / 24, c4 = t % 24;  // c4: uint4 index (channels 8c4..8c4+7)
    const uint4* base = (const uint4*)(xt + (size_t)b * NN * CC) + c4;
    float mx[8];
    #pragma unroll
    for (int c = 0; c < 8; ++c) mx[c] = -INFINITY;
    #pragma unroll
    for (int k = 0; k < KK; ++k) {
        uint4 vj = base[(size_t)sj[p][k] * 24];
        uint4 vi = base[(size_t)si[p][k] * 24];
        const unsigned int dj[4] = {vj.x, vj.y, vj.z, vj.w};
        const unsigned int di[4] = {vi.x, vi.y, vi.z, vi.w};
        #pragma unroll
        for (int d = 0; d < 4; ++d) {
            mx[2 * d]     = fmaxf(mx[2 * d],     bf16_to_f32(dj[d] & 0xffffu) - bf16_to_f32(di[d] & 0xffffu));
            mx[2 * d + 1] = fmaxf(mx[2 * d + 1], bf16hi_to_f32(dj[d]) - bf16hi_to_f32(di[d]));
        }
    }
    uint4 xs = base[(size_t)(n0 + p) * 24];
    uint4 o0, o1;
    o0.x = (xs.x & 0xffffu) | ((unsigned int)f32_to_bf16(mx[0]) << 16);
    o0.y = (xs.x >> 16)     | ((unsigned int)f32_to_bf16(mx[1]) << 16);
    o0.z = (xs.y & 0xffffu) | ((unsigned int)f32_to_bf16(mx[2]) << 16);
    o0.w = (xs.y >> 16)     | ((unsigned int)f32_to_bf16(mx[3]) << 16);
    o1.x = (xs.z & 0xffffu) | ((unsigned int)f32_to_bf16(mx[4]) << 16);
    o1.y = (xs.z >> 16)     | ((unsigned int)f32_to_bf16(mx[5]) << 16);
    o1.z = (xs.w & 0xffffu) | ((unsigned int)f32_to_bf16(mx[6]) << 16);
    o1.w = (xs.w >> 16)     | ((unsigned int)f32_to_bf16(mx[7]) << 16);
    size_t orow = (size_t)(m0 + p) * 48;
    xcat4[orow + 2 * c4] = o0;
    xcat4[orow + 2 * c4 + 1] = o1;
}

// ---------------------------------------------------------------------------
// Kernel 3 (k_gemm): MFMA GEMM h[m][o] = sum_k xcat[m][k]*Wb[o][k].
// Staging now via global_load_lds width=16 (DMA, no VGPR round-trip):
// linear LDS dest (wave-uniform base + lane*16) + INVERSE-swizzled global
// source (cg = c ^ (r&7)), so the swizzled ds_read_b128 compute reads are
// unchanged (rule 21: both-sides-or-neither).
// Grid 256 (1 block/CU), 512 threads, BM=128 x O=192, BK=64.
// ---------------------------------------------------------------------------
#define BMT 128
__global__ __launch_bounds__(512) void k_gemm(const unsigned short* __restrict__ xcat,
                                              const unsigned short* __restrict__ Wb,
                                              unsigned short* __restrict__ h,
                                              float* __restrict__ psum,
                                              float* __restrict__ psum2) {
    __shared__ __align__(16) char ldsA[BMT * 128];    // 16 KB (reused for reduce)
    __shared__ __align__(16) char ldsB[COUT * 128];   // 24 KB
    int t = threadIdx.x;
    int m0 = blockIdx.x * BMT;
    int w = t >> 6, l = t & 63, lo = l & 15, q4 = l >> 4;
    int lr = l >> 3, lc = l & 7;   // staging: row-in-8-group, chunk
    f32x4 acc[12];
    #pragma unroll
    for (int i = 0; i < 12; ++i) acc[i] = (f32x4){0.f, 0.f, 0.f, 0.f};
    int rA = w * 16 + lo;

    for (int ks = 0; ks < KDIM / 64; ++ks) {
        int k0 = ks * 64;
        if (ks) __syncthreads();
        // stage A: wave w -> LDS rows 16w..16w+15 (2 calls x 8 rows)
        #pragma unroll
        for (int e = 0; e < 2; ++e) {
            int r = w * 16 + e * 8 + lr;
            int cg = lc ^ (r & 7);
            const unsigned short* gp = xcat + (size_t)(m0 + r) * KDIM + k0 + cg * 8;
            __builtin_amdgcn_global_load_lds((AS1P)gp, (AS3P)(ldsA + w * 2048 + e * 1024), 16, 0, 0);
        }
        // stage B: wave w -> LDS rows 24w..24w+23 (3 calls x 8 rows)
        #pragma unroll
        for (int e = 0; e < 3; ++e) {
            int r = w * 24 + e * 8 + lr;
            int cg = lc ^ (r & 7);
            const unsigned short* gp = Wb + (size_t)r * KDIM + k0 + cg * 8;
            __builtin_amdgcn_global_load_lds((AS1P)gp, (AS3P)(ldsB + w * 3072 + e * 1024), 16, 0, 0);
        }
        __syncthreads();
        #pragma unroll
        for (int kh = 0; kh < 2; ++kh) {
            int cb = kh * 64 + q4 * 16;
            short8 a = *(const short8*)(ldsA + rA * 128 + (cb ^ ((rA & 7) << 4)));
            #pragma unroll
            for (int ot = 0; ot < 12; ++ot) {
                int rB = ot * 16 + lo;
                short8 bf = *(const short8*)(ldsB + rB * 128 + (cb ^ ((rB & 7) << 4)));
                acc[ot] = __builtin_amdgcn_mfma_f32_16x16x32_bf16(a, bf, acc[ot], 0, 0, 0);
            }
        }
    }
    __syncthreads();  // all waves done with ldsA before the reduce overlay

    // epilogue: h (bf16) + per-wave BN sums into LDS. C/D: o=lane&15, m=q4*4+r
    float* reds = (float*)ldsA;              // [8][COUT]
    float* reds2 = reds + 8 * COUT;          // [8][COUT]
    int mrow = m0 + w * 16 + q4 * 4;
    #pragma unroll
    for (int ot = 0; ot < 12; ++ot) {
        int o = ot * 16 + lo;
        float s = 0.f, s2 = 0.f;
        #pragma unroll
        for (int r = 0; r < 4; ++r) {
            float v = acc[ot][r];
            h[(size_t)(mrow + r) * COUT + o] = f32_to_bf16(v);
            s += v;
            s2 += v * v;
        }
        s += __shfl_xor(s, 16);  s2 += __shfl_xor(s2, 16);
        s += __shfl_xor(s, 32);  s2 += __shfl_xor(s2, 32);
        if (q4 == 0) {
            reds[w * COUT + o] = s;
            reds2[w * COUT + o] = s2;
        }
    }
    __syncthreads();
    if (t < COUT) {
        float a = 0.f, a2 = 0.f;
        #pragma unroll
        for (int w8 = 0; w8 < 8; ++w8) {
            a += reds[w8 * COUT + t];
            a2 += reds2[w8 * COUT + t];
        }
        psum[blockIdx.x * COUT + t] = a;
        psum2[blockIdx.x * COUT + t] = a2;
    }
}

// ---------------------------------------------------------------------------
// Kernel 4 (k_bn): parallel partial reduce. Grid 24 blocks x 256 threads;
// block owns 8 channels, reads all 256 partial rows for them, writes sc_sh.
// (Round-7's single-block version serialized 393 KB through one CU.)
// ---------------------------------------------------------------------------
__global__ __launch_bounds__(256) void k_bn(const float* __restrict__ psum,
                                            const float* __restrict__ psum2,
                                            const float* __restrict__ gamma,
                                            const float* __restrict__ beta,
                                            float* __restrict__ sc_sh) {
    __shared__ float red[2][32][8];
    int t = threadIdx.x;
    int ch = t & 7, rr = t >> 3;      // 8 channels x 32 row-groups
    int o = blockIdx.x * 8 + ch;
    float a = 0.f, a2 = 0.f;
    for (int r = rr; r < NGB; r += 32) {
        a += psum[r * COUT + o];
        a2 += psum2[r * COUT + o];
    }
    red[0][rr][ch] = a;
    red[1][rr][ch] = a2;
    __syncthreads();
    if (t < 8) {
        float s = 0.f, s2 = 0.f;
        #pragma unroll
        for (int i = 0; i < 32; ++i) { s += red[0][i][t]; s2 += red[1][i][t]; }
        int oo = blockIdx.x * 8 + t;
        float inv_m = 1.0f / (float)MM;
        float mean = s * inv_m;
        float var = s2 * inv_m - mean * mean;
        float sc = gamma[oo] * rsqrtf(var + EPSF);
        sc_sh[oo] = sc;
        sc_sh[COUT + oo] = beta[oo] - mean * sc;
    }
}

// ---------------------------------------------------------------------------
// Kernel 5 (k_out): BN apply + exact GELU + transpose h [m][o] -> out [B,O,N]
// ---------------------------------------------------------------------------
__global__ __launch_bounds__(256) void k_out(const unsigned short* __restrict__ h,
                                             const float* __restrict__ sc_sh,
                                             float* __restrict__ out) {
    __shared__ float tile[32][33];
    int b = blockIdx.z;
    int n0 = blockIdx.x * 32;
    int o0 = blockIdx.y * 32;
    int tx = threadIdx.x, ty = threadIdx.y;  // (32,8)
    int o = o0 + tx;
    float sc = sc_sh[o];
    float sh = sc_sh[COUT + o];
    #pragma unroll
    for (int j = 0; j < 32; j += 8) {
        float v = bf16_to_f32(h[((size_t)b * NN + n0 + ty + j) * COUT + o]);
        v = v * sc + sh;
        tile[ty + j][tx] = 0.5f * v * (1.0f + erff(v * 0.70710678118654752440f));
    }
    __syncthreads();
    #pragma unroll
    for (int j = 0; j < 32; j += 8)
        out[((size_t)b * COUT + (o0 + ty + j)) * NN + n0 + tx] = tile[tx][ty + j];
}

// ---------------------------------------------------------------------------
extern "C" void kernel_launch(void* const* d_in, const int* in_sizes, int n_in,
                              void* d_out, int out_size, void* d_ws, size_t ws_size,
                              hipStream_t stream) {
    const float* x = (const float*)d_in[0];
    const float* W = (const float*)d_in[1];
    // d_in[2] = b_conv: cancels in training-mode BN
    const float* gamma = (const float*)d_in[3];
    const float* beta = (const float*)d_in[4];
    const int* edge = (const int*)d_in[5];
    float* out = (float*)d_out;

    char* ws = (char*)d_ws;
    unsigned short* xt = (unsigned short*)ws;                 // [M][C] bf16
    ws += (size_t)MM * CC * 2;
    unsigned short* xcat = (unsigned short*)ws;               // [M][2C] bf16
    ws += (size_t)MM * KDIM * 2;
    unsigned short* Wb = (unsigned short*)ws;                 // [COUT][2C] bf16
    ws += (size_t)COUT * KDIM * 2;
    unsigned short* h = (unsigned short*)ws;                  // [M][COUT] bf16
    ws += (size_t)MM * COUT * 2;
    float* psum = (float*)ws;                                 // [NGB][COUT]
    ws += (size_t)NGB * COUT * sizeof(float);
    float* psum2 = (float*)ws;                                // [NGB][COUT]
    ws += (size_t)NGB * COUT * sizeof(float);
    float* sc_sh = (float*)ws;                                // [2*COUT]

    k_prep<<<TRB + 72, 256, 0, stream>>>(x, (unsigned int*)xt, W, Wb);

    k_gather<<<MM / 16, 384, 0, stream>>>(xt, edge, (uint4*)xcat);

    k_gemm<<<MM / BMT, 512, 0, stream>>>(xcat, Wb, h, psum, psum2);

    k_bn<<<24, 256, 0, stream>>>(psum, psum2, gamma, beta, sc_sh);

    dim3 ogrid(NN / 32, COUT / 32, BB);
    k_out<<<ogrid, dim3(32, 8), 0, stream>>>(h, sc_sh, out);
}